// Round 3
// baseline (1547.154 us; speedup 1.0000x reference)
//
#include <hip/hip_runtime.h>
#include <hip/hip_bf16.h>

typedef __hip_bfloat16 bf16;

#define D 128
#define N_CLS 40

__device__ inline float b2f(unsigned short u) {
  union { unsigned int i; float f; } c;
  c.i = ((unsigned int)u) << 16;
  return c.f;
}
__device__ inline unsigned short f2b(float f) {
  union { float f; unsigned int i; } c;
  c.f = f;
  unsigned int r = c.i + 0x7FFF + ((c.i >> 16) & 1);  // round-to-nearest-even
  return (unsigned short)(r >> 16);
}

// ---------------- degree count ----------------
__global__ void k_count(const int* __restrict__ dst, int* __restrict__ deg, int e) {
  int i = blockIdx.x * blockDim.x + threadIdx.x;
  if (i < e) atomicAdd(&deg[dst[i]], 1);
}

// ---------------- exclusive scan over n degrees (single block) ----------------
__global__ __launch_bounds__(1024) void k_scan(const int* __restrict__ deg,
                                               int* __restrict__ cursor,
                                               float* __restrict__ isd, int n) {
  __shared__ int sums[1024];
  int t = threadIdx.x;
  int ch = (n + 1023) >> 10;
  int base = t * ch;
  int s = 0;
  for (int k = 0; k < ch; ++k) {
    int idx = base + k;
    if (idx < n) s += deg[idx];
  }
  sums[t] = s;
  __syncthreads();
  for (int off = 1; off < 1024; off <<= 1) {
    int add = (t >= off) ? sums[t - off] : 0;
    __syncthreads();
    sums[t] += add;
    __syncthreads();
  }
  int run = sums[t] - s;
  for (int k = 0; k < ch; ++k) {
    int idx = base + k;
    if (idx < n) {
      int d = deg[idx];
      cursor[idx] = run;
      isd[idx] = rsqrtf((float)(d + 1));  // +1 self-loop
      run += d;
    }
  }
}

// ---------------- scatter edges into CSR buckets ----------------
__global__ void k_scatter(const int* __restrict__ src, const int* __restrict__ dst,
                          int* __restrict__ cursor, int* __restrict__ csr_src, int e) {
  int i = blockIdx.x * blockDim.x + threadIdx.x;
  if (i < e) {
    int p = atomicAdd(&cursor[dst[i]], 1);
    csr_src[p] = src[i];
  }
}

// ---------------- HS = isd[i] * (X @ W); X fp32, W fp32, HS bf16 ----------------
__global__ __launch_bounds__(128) void k_gemm_f32(const float* __restrict__ X,
                                                  const float* __restrict__ W,
                                                  const float* __restrict__ isd,
                                                  bf16* __restrict__ HS) {
  int i = blockIdx.x, j = threadIdx.x;
  __shared__ float row[D];
  row[j] = X[(size_t)i * D + j];
  __syncthreads();
  float acc = 0.f;
#pragma unroll 8
  for (int k = 0; k < D; ++k) acc += row[k] * W[k * D + j];
  ((unsigned short*)HS)[(size_t)i * D + j] = f2b(isd[i] * acc);
}

// ---------------- HS = isd[i] * (G @ W); G bf16, W fp32, HS bf16 ----------------
__global__ __launch_bounds__(128) void k_gemm_bf(const bf16* __restrict__ G,
                                                 const float* __restrict__ W,
                                                 const float* __restrict__ isd,
                                                 bf16* __restrict__ HS) {
  int i = blockIdx.x, j = threadIdx.x;
  __shared__ float row[D];
  row[j] = b2f(((const unsigned short*)G)[(size_t)i * D + j]);
  __syncthreads();
  float acc = 0.f;
#pragma unroll 8
  for (int k = 0; k < D; ++k) acc += row[k] * W[k * D + j];
  ((unsigned short*)HS)[(size_t)i * D + j] = f2b(isd[i] * acc);
}

// ---------------- G = relu(isd[i]*(sum_{e->i} hs[s] + hs[i]) + b), bf16 out ----------------
__global__ __launch_bounds__(64) void k_agg1(const bf16* __restrict__ HS,
                                             const int* __restrict__ csr_src,
                                             const int* __restrict__ cursor,
                                             const int* __restrict__ deg,
                                             const float* __restrict__ isd,
                                             const float* __restrict__ bias,
                                             bf16* __restrict__ G) {
  int i = blockIdx.x;
  int f = threadIdx.x;  // 64 threads, features {2f, 2f+1}
  const ushort2* hs2 = (const ushort2*)HS;
  ushort2 v = hs2[(size_t)i * 64 + f];  // self-loop term
  float ax = b2f(v.x), ay = b2f(v.y);
  int c = deg[i];
  int start = cursor[i] - c;  // cursor advanced by scatter
  for (int e0 = 0; e0 < c; e0 += 64) {
    int nb = min(64, c - e0);
    int idx = (f < nb) ? csr_src[start + e0 + f] : 0;
    for (int k = 0; k < nb; ++k) {
      int s = __shfl(idx, k);
      ushort2 u = hs2[(size_t)s * 64 + f];
      ax += b2f(u.x);
      ay += b2f(u.y);
    }
  }
  float di = isd[i];
  float gx = di * ax + bias[2 * f];
  float gy = di * ay + bias[2 * f + 1];
  gx = gx > 0.f ? gx : 0.f;
  gy = gy > 0.f ? gy : 0.f;
  ushort2 o;
  o.x = f2b(gx);
  o.y = f2b(gy);
  ((ushort2*)G)[(size_t)i * 64 + f] = o;
}

// ---------------- agg + bias + relu + classifier -> fp32 out ----------------
__global__ __launch_bounds__(64) void k_agg_cls(const bf16* __restrict__ HS,
                                                const int* __restrict__ csr_src,
                                                const int* __restrict__ cursor,
                                                const int* __restrict__ deg,
                                                const float* __restrict__ isd,
                                                const float* __restrict__ b2,
                                                const float* __restrict__ Wl,
                                                const float* __restrict__ bl,
                                                float* __restrict__ out) {
  int i = blockIdx.x;
  int f = threadIdx.x;
  const ushort2* hs2 = (const ushort2*)HS;
  ushort2 v = hs2[(size_t)i * 64 + f];
  float ax = b2f(v.x), ay = b2f(v.y);
  int c = deg[i];
  int start = cursor[i] - c;
  for (int e0 = 0; e0 < c; e0 += 64) {
    int nb = min(64, c - e0);
    int idx = (f < nb) ? csr_src[start + e0 + f] : 0;
    for (int k = 0; k < nb; ++k) {
      int s = __shfl(idx, k);
      ushort2 u = hs2[(size_t)s * 64 + f];
      ax += b2f(u.x);
      ay += b2f(u.y);
    }
  }
  float di = isd[i];
  float gx = di * ax + b2[2 * f];
  float gy = di * ay + b2[2 * f + 1];
  gx = gx > 0.f ? gx : 0.f;
  gy = gy > 0.f ? gy : 0.f;
  __shared__ float t[D];
  t[2 * f] = gx;
  t[2 * f + 1] = gy;
  __syncthreads();
  if (f < N_CLS) {
    float o = bl[f];
#pragma unroll 8
    for (int k = 0; k < D; ++k) o += t[k] * Wl[k * N_CLS + f];
    out[(size_t)i * N_CLS + f] = o;
  }
}

extern "C" void kernel_launch(void* const* d_in, const int* in_sizes, int n_in,
                              void* d_out, int out_size, void* d_ws, size_t ws_size,
                              hipStream_t stream) {
  const float* x  = (const float*)d_in[0];
  const int*   ei = (const int*)d_in[1];
  const float* W1 = (const float*)d_in[2];
  const float* b1 = (const float*)d_in[3];
  const float* W2 = (const float*)d_in[4];
  const float* b2 = (const float*)d_in[5];
  const float* Wl = (const float*)d_in[6];
  const float* bl = (const float*)d_in[7];
  float* out = (float*)d_out;

  const int n = in_sizes[0] / D;  // 100000
  const int e = in_sizes[1] / 2;  // 3200000
  const int* src = ei;
  const int* dst = ei + e;

  // workspace (~65 MB): deg|cursor|isd (1.2MB) + csr_src 12.8MB + hA/hB 25.6MB each
  char* ws = (char*)d_ws;
  size_t off = 0;
  auto alloc = [&](size_t bytes) -> void* {
    void* p = ws + off;
    off += (bytes + 255) & ~(size_t)255;
    return p;
  };
  int*   deg     = (int*)alloc((size_t)n * 4);
  int*   cursor  = (int*)alloc((size_t)n * 4);
  float* isd     = (float*)alloc((size_t)n * 4);
  int*   csr_src = (int*)alloc((size_t)e * 4);
  bf16*  hA      = (bf16*)alloc((size_t)n * D * 2);
  bf16*  hB      = (bf16*)alloc((size_t)n * D * 2);

  hipMemsetAsync(deg, 0, (size_t)n * 4, stream);

  const int tb = 256;
  k_count<<<(e + tb - 1) / tb, tb, 0, stream>>>(dst, deg, e);
  k_scan<<<1, 1024, 0, stream>>>(deg, cursor, isd, n);
  k_scatter<<<(e + tb - 1) / tb, tb, 0, stream>>>(src, dst, cursor, csr_src, e);

  // layer 1
  k_gemm_f32<<<n, D, 0, stream>>>(x, W1, isd, hA);
  k_agg1<<<n, 64, 0, stream>>>(hA, csr_src, cursor, deg, isd, b1, hB);
  // layer 2 + classifier
  k_gemm_bf<<<n, D, 0, stream>>>(hB, W2, isd, hA);
  k_agg_cls<<<n, 64, 0, stream>>>(hA, csr_src, cursor, deg, isd, b2, Wl, bl, out);
}

// Round 4
// 740.966 us; speedup vs baseline: 2.0880x; 2.0880x over previous
//
#include <hip/hip_runtime.h>
#include <hip/hip_bf16.h>

typedef __hip_bfloat16 bf16;

#define D 128
#define N_CLS 40
#define BN 128       // nodes per bucket
#define NBMAX 1024   // padded bucket count

__device__ inline float b2f(unsigned int u) {
  union { unsigned int i; float f; } c;
  c.i = u << 16;
  return c.f;
}
__device__ inline unsigned short f2b(float f) {
  union { float f; unsigned int i; } c;
  c.f = f;
  unsigned int r = c.i + 0x7FFF + ((c.i >> 16) & 1);  // RNE
  return (unsigned short)(r >> 16);
}

// ---- 1. bucket histogram of dst (LDS-staged) ----
__global__ __launch_bounds__(256) void k_hist(const int* __restrict__ dst,
                                              int* __restrict__ bcnt, int e) {
  __shared__ int lh[NBMAX];
  for (int j = threadIdx.x; j < NBMAX; j += 256) lh[j] = 0;
  __syncthreads();
  int stride = gridDim.x * blockDim.x;
  for (int q = blockIdx.x * blockDim.x + threadIdx.x; q < e; q += stride)
    atomicAdd(&lh[dst[q] >> 7], 1);
  __syncthreads();
  for (int j = threadIdx.x; j < NBMAX; j += 256)
    if (lh[j]) atomicAdd(&bcnt[j], lh[j]);
}

// ---- 2. exclusive scan of bucket counts ----
__global__ __launch_bounds__(1024) void k_bscan(const int* __restrict__ bcnt,
                                                int* __restrict__ bbase,
                                                int* __restrict__ bcur) {
  __shared__ int sums[NBMAX];
  int t = threadIdx.x;
  int c = bcnt[t];
  sums[t] = c;
  __syncthreads();
  for (int off = 1; off < NBMAX; off <<= 1) {
    int a = (t >= off) ? sums[t - off] : 0;
    __syncthreads();
    sums[t] += a;
    __syncthreads();
  }
  bbase[t] = sums[t] - c;
  bcur[t] = sums[t] - c;
}

// ---- 3. bin edges into bucket-major order (dense per-wg reservations) ----
__global__ __launch_bounds__(256) void k_place(const int* __restrict__ src,
                                               const int* __restrict__ dst,
                                               int* __restrict__ bcur,
                                               unsigned int* __restrict__ binned,
                                               int e, int nwg) {
  __shared__ int lh[NBMAX];
  __shared__ int lofs[NBMAX];
  __shared__ int lcur[NBMAX];
  int chunk = (e + nwg - 1) / nwg;
  int lo = blockIdx.x * chunk;
  int hi = min(e, lo + chunk);
  int t = threadIdx.x;
  for (int j = t; j < NBMAX; j += 256) { lh[j] = 0; lcur[j] = 0; }
  __syncthreads();
  for (int q = lo + t; q < hi; q += 256) atomicAdd(&lh[dst[q] >> 7], 1);
  __syncthreads();
  for (int j = t; j < NBMAX; j += 256) {
    int c = lh[j];
    lofs[j] = c ? atomicAdd(&bcur[j], c) : 0;
  }
  __syncthreads();
  for (int q = lo + t; q < hi; q += 256) {
    int d = dst[q];
    int b = d >> 7;
    int r = atomicAdd(&lcur[b], 1);
    binned[lofs[b] + r] = ((unsigned int)(d & 127) << 17) | (unsigned int)src[q];
  }
}

// ---- 4. per-bucket counting sort -> CSR + deg + isd + row_start ----
__global__ __launch_bounds__(256) void k_csr(const unsigned int* __restrict__ binned,
                                             const int* __restrict__ bbase,
                                             int* __restrict__ csr,
                                             int* __restrict__ deg,
                                             float* __restrict__ isd,
                                             int* __restrict__ row_start, int n) {
  int b = blockIdx.x;
  int lo = bbase[b], hi = bbase[b + 1];
  __shared__ int h[BN];
  __shared__ int sc[BN];
  __shared__ int cur[BN];
  int t = threadIdx.x;
  if (t < BN) h[t] = 0;
  __syncthreads();
  for (int q = lo + t; q < hi; q += 256) atomicAdd(&h[binned[q] >> 17], 1);
  __syncthreads();
  if (t < BN) sc[t] = h[t];
  __syncthreads();
  for (int off = 1; off < BN; off <<= 1) {
    int a = 0;
    if (t < BN && t >= off) a = sc[t - off];
    __syncthreads();
    if (t < BN) sc[t] += a;
    __syncthreads();
  }
  if (t < BN) {
    int excl = sc[t] - h[t];
    cur[t] = lo + excl;
    int i = b * BN + t;
    if (i < n) {
      deg[i] = h[t];
      isd[i] = rsqrtf((float)(h[t] + 1));
      row_start[i] = lo + excl;
    }
  }
  __syncthreads();
  for (int q = lo + t; q < hi; q += 256) {
    unsigned int u = binned[q];
    int p = atomicAdd(&cur[u >> 17], 1);
    csr[p] = (int)(u & 0x1FFFF);
  }
}

// ---- tiled GEMM: HS = isd[i] * (X @ W), fp32 accum, bf16 out ----
// 64 rows/block, 256 threads, each thread 4 rows x 8 cols
template <bool BF>
__global__ __launch_bounds__(256) void k_gemm_t(const void* __restrict__ Xv,
                                                const float* __restrict__ W,
                                                const float* __restrict__ isd,
                                                bf16* __restrict__ HS, int n) {
  __shared__ float Xt[64][D + 4];
  __shared__ float Wb[32][D + 4];
  int t = threadIdx.x;
  int r0 = blockIdx.x * 64;
  if (!BF) {
    const float* X = (const float*)Xv;
    for (int q = t; q < 64 * 32; q += 256) {  // 32 float4 per row
      int row = q >> 5, cb = (q & 31) << 2;
      float4 v = {0.f, 0.f, 0.f, 0.f};
      if (r0 + row < n) v = *(const float4*)(X + (size_t)(r0 + row) * D + cb);
      *(float4*)&Xt[row][cb] = v;
    }
  } else {
    const unsigned short* X = (const unsigned short*)Xv;
    for (int q = t; q < 64 * 16; q += 256) {  // 16 uint4 per row (8 bf16 each)
      int row = q >> 4, cb = (q & 15) << 3;
      uint4 v = {0u, 0u, 0u, 0u};
      if (r0 + row < n) v = *(const uint4*)(X + (size_t)(r0 + row) * D + cb);
      float* xp = &Xt[row][cb];
      xp[0] = b2f(v.x & 0xFFFF); xp[1] = b2f(v.x >> 16);
      xp[2] = b2f(v.y & 0xFFFF); xp[3] = b2f(v.y >> 16);
      xp[4] = b2f(v.z & 0xFFFF); xp[5] = b2f(v.z >> 16);
      xp[6] = b2f(v.w & 0xFFFF); xp[7] = b2f(v.w >> 16);
    }
  }
  int tr = ((t >> 4) & 15) << 2;  // row base 0..60
  int tc = (t & 15) << 3;         // col base 0..120
  float acc[4][8];
#pragma unroll
  for (int i = 0; i < 4; ++i)
#pragma unroll
    for (int j = 0; j < 8; ++j) acc[i][j] = 0.f;

  for (int hh = 0; hh < 4; ++hh) {
    __syncthreads();
    for (int q = t; q < 32 * 32; q += 256) {  // stage 32 K-rows of W
      int row = q >> 5, cb = (q & 31) << 2;
      *(float4*)&Wb[row][cb] = *(const float4*)(W + (size_t)(hh * 32 + row) * D + cb);
    }
    __syncthreads();
#pragma unroll 4
    for (int k = 0; k < 32; ++k) {
      float4 u0 = *(const float4*)&Wb[k][tc];
      float4 u1 = *(const float4*)&Wb[k][tc + 4];
      float bv[8] = {u0.x, u0.y, u0.z, u0.w, u1.x, u1.y, u1.z, u1.w};
      int kk = hh * 32 + k;
#pragma unroll
      for (int i = 0; i < 4; ++i) {
        float a = Xt[tr + i][kk];
#pragma unroll
        for (int j = 0; j < 8; ++j) acc[i][j] += a * bv[j];
      }
    }
  }
#pragma unroll
  for (int i = 0; i < 4; ++i) {
    int row = r0 + tr + i;
    if (row < n) {
      float s = isd[row];
      unsigned short o[8];
#pragma unroll
      for (int j = 0; j < 8; ++j) o[j] = f2b(s * acc[i][j]);
      unsigned short* hp = (unsigned short*)HS + (size_t)row * D + tc;
      *(ushort4*)hp = *(ushort4*)&o[0];
      *(ushort4*)(hp + 4) = *(ushort4*)&o[4];
    }
  }
}

// ---- agg + bias + relu -> bf16 ----
__global__ __launch_bounds__(64) void k_agg1(const bf16* __restrict__ HS,
                                             const int* __restrict__ csr,
                                             const int* __restrict__ row_start,
                                             const int* __restrict__ deg,
                                             const float* __restrict__ isd,
                                             const float* __restrict__ bias,
                                             bf16* __restrict__ G) {
  int i = blockIdx.x;
  int f = threadIdx.x;
  const ushort2* hs2 = (const ushort2*)HS;
  ushort2 v = hs2[(size_t)i * 64 + f];  // self-loop term (already isd[i]-scaled)
  float ax = b2f(v.x), ay = b2f(v.y);
  int c = deg[i];
  int start = row_start[i];
  for (int e0 = 0; e0 < c; e0 += 64) {
    int nb = min(64, c - e0);
    int idx = (f < nb) ? csr[start + e0 + f] : 0;
    for (int k = 0; k < nb; ++k) {
      int s = __shfl(idx, k);
      ushort2 u = hs2[(size_t)s * 64 + f];
      ax += b2f(u.x);
      ay += b2f(u.y);
    }
  }
  float di = isd[i];
  float gx = di * ax + bias[2 * f];
  float gy = di * ay + bias[2 * f + 1];
  gx = gx > 0.f ? gx : 0.f;
  gy = gy > 0.f ? gy : 0.f;
  ushort2 o;
  o.x = f2b(gx);
  o.y = f2b(gy);
  ((ushort2*)G)[(size_t)i * 64 + f] = o;
}

// ---- agg + bias + relu + classifier -> fp32 out ----
__global__ __launch_bounds__(64) void k_agg_cls(const bf16* __restrict__ HS,
                                                const int* __restrict__ csr,
                                                const int* __restrict__ row_start,
                                                const int* __restrict__ deg,
                                                const float* __restrict__ isd,
                                                const float* __restrict__ b2,
                                                const float* __restrict__ Wl,
                                                const float* __restrict__ bl,
                                                float* __restrict__ out) {
  int i = blockIdx.x;
  int f = threadIdx.x;
  const ushort2* hs2 = (const ushort2*)HS;
  ushort2 v = hs2[(size_t)i * 64 + f];
  float ax = b2f(v.x), ay = b2f(v.y);
  int c = deg[i];
  int start = row_start[i];
  for (int e0 = 0; e0 < c; e0 += 64) {
    int nb = min(64, c - e0);
    int idx = (f < nb) ? csr[start + e0 + f] : 0;
    for (int k = 0; k < nb; ++k) {
      int s = __shfl(idx, k);
      ushort2 u = hs2[(size_t)s * 64 + f];
      ax += b2f(u.x);
      ay += b2f(u.y);
    }
  }
  float di = isd[i];
  float gx = di * ax + b2[2 * f];
  float gy = di * ay + b2[2 * f + 1];
  gx = gx > 0.f ? gx : 0.f;
  gy = gy > 0.f ? gy : 0.f;
  __shared__ float tt[D];
  tt[2 * f] = gx;
  tt[2 * f + 1] = gy;
  __syncthreads();
  if (f < N_CLS) {
    float o = bl[f];
#pragma unroll 8
    for (int k = 0; k < D; ++k) o += tt[k] * Wl[k * N_CLS + f];
    out[(size_t)i * N_CLS + f] = o;
  }
}

extern "C" void kernel_launch(void* const* d_in, const int* in_sizes, int n_in,
                              void* d_out, int out_size, void* d_ws, size_t ws_size,
                              hipStream_t stream) {
  const float* x  = (const float*)d_in[0];
  const int*   ei = (const int*)d_in[1];
  const float* W1 = (const float*)d_in[2];
  const float* b1 = (const float*)d_in[3];
  const float* W2 = (const float*)d_in[4];
  const float* b2 = (const float*)d_in[5];
  const float* Wl = (const float*)d_in[6];
  const float* bl = (const float*)d_in[7];
  float* out = (float*)d_out;

  const int n = in_sizes[0] / D;  // 100000
  const int e = in_sizes[1] / 2;  // 3200000
  const int* src = ei;
  const int* dst = ei + e;
  const int nb = (n + BN - 1) / BN;  // 782

  char* ws = (char*)d_ws;
  size_t off = 0;
  auto alloc = [&](size_t bytes) -> void* {
    void* p = ws + off;
    off += (bytes + 255) & ~(size_t)255;
    return p;
  };
  int*   bcnt      = (int*)alloc(NBMAX * 4);
  int*   bbase     = (int*)alloc(NBMAX * 4);
  int*   bcur      = (int*)alloc(NBMAX * 4);
  int*   deg       = (int*)alloc((size_t)n * 4);
  int*   row_start = (int*)alloc((size_t)n * 4);
  float* isd       = (float*)alloc((size_t)n * 4);
  int*   csr       = (int*)alloc((size_t)e * 4);
  bf16*  hA        = (bf16*)alloc((size_t)n * D * 2);
  bf16*  hB        = (bf16*)alloc((size_t)n * D * 2);
  unsigned int* binned = (unsigned int*)hA;  // dead before gemm1 writes hA

  hipMemsetAsync(bcnt, 0, NBMAX * 4, stream);

  const int nwg_place = 256;
  k_hist<<<1024, 256, 0, stream>>>(dst, bcnt, e);
  k_bscan<<<1, 1024, 0, stream>>>(bcnt, bbase, bcur);
  k_place<<<nwg_place, 256, 0, stream>>>(src, dst, bcur, binned, e, nwg_place);
  k_csr<<<nb, 256, 0, stream>>>(binned, bbase, csr, deg, isd, row_start, n);

  int gblocks = (n + 63) / 64;
  // layer 1
  k_gemm_t<false><<<gblocks, 256, 0, stream>>>(x, W1, isd, hA, n);
  k_agg1<<<n, 64, 0, stream>>>(hA, csr, row_start, deg, isd, b1, hB);
  // layer 2 + classifier
  k_gemm_t<true><<<gblocks, 256, 0, stream>>>(hB, W2, isd, hA, n);
  k_agg_cls<<<n, 64, 0, stream>>>(hA, csr, row_start, deg, isd, b2, Wl, bl, out);
}

// Round 5
// 587.265 us; speedup vs baseline: 2.6345x; 1.2617x over previous
//
#include <hip/hip_runtime.h>
#include <hip/hip_bf16.h>

typedef __hip_bfloat16 bf16;

#define D 128
#define N_CLS 40
#define BN 128       // nodes per bucket
#define NBMAX 1024   // padded bucket count

__device__ inline float b2f(unsigned int u) {
  union { unsigned int i; float f; } c;
  c.i = u << 16;
  return c.f;
}
__device__ inline unsigned short f2b(float f) {
  union { float f; unsigned int i; } c;
  c.f = f;
  unsigned int r = c.i + 0x7FFF + ((c.i >> 16) & 1);  // RNE
  return (unsigned short)(r >> 16);
}

// ---- 1. bucket histogram of dst (LDS-staged) ----
__global__ __launch_bounds__(256) void k_hist(const int* __restrict__ dst,
                                              int* __restrict__ bcnt, int e) {
  __shared__ int lh[NBMAX];
  for (int j = threadIdx.x; j < NBMAX; j += 256) lh[j] = 0;
  __syncthreads();
  int stride = gridDim.x * blockDim.x;
  for (int q = blockIdx.x * blockDim.x + threadIdx.x; q < e; q += stride)
    atomicAdd(&lh[dst[q] >> 7], 1);
  __syncthreads();
  for (int j = threadIdx.x; j < NBMAX; j += 256)
    if (lh[j]) atomicAdd(&bcnt[j], lh[j]);
}

// ---- 2. exclusive scan of bucket counts ----
__global__ __launch_bounds__(1024) void k_bscan(const int* __restrict__ bcnt,
                                                int* __restrict__ bbase,
                                                int* __restrict__ bcur) {
  __shared__ int sums[NBMAX];
  int t = threadIdx.x;
  int c = bcnt[t];
  sums[t] = c;
  __syncthreads();
  for (int off = 1; off < NBMAX; off <<= 1) {
    int a = (t >= off) ? sums[t - off] : 0;
    __syncthreads();
    sums[t] += a;
    __syncthreads();
  }
  bbase[t] = sums[t] - c;
  bcur[t] = sums[t] - c;
}

// ---- 3. bin edges into bucket-major order (dense per-wg reservations) ----
__global__ __launch_bounds__(256) void k_place(const int* __restrict__ src,
                                               const int* __restrict__ dst,
                                               int* __restrict__ bcur,
                                               unsigned int* __restrict__ binned,
                                               int e, int nwg) {
  __shared__ int lh[NBMAX];
  __shared__ int lofs[NBMAX];
  __shared__ int lcur[NBMAX];
  int chunk = (e + nwg - 1) / nwg;
  int lo = blockIdx.x * chunk;
  int hi = min(e, lo + chunk);
  int t = threadIdx.x;
  for (int j = t; j < NBMAX; j += 256) { lh[j] = 0; lcur[j] = 0; }
  __syncthreads();
  for (int q = lo + t; q < hi; q += 256) atomicAdd(&lh[dst[q] >> 7], 1);
  __syncthreads();
  for (int j = t; j < NBMAX; j += 256) {
    int c = lh[j];
    lofs[j] = c ? atomicAdd(&bcur[j], c) : 0;
  }
  __syncthreads();
  for (int q = lo + t; q < hi; q += 256) {
    int d = dst[q];
    int b = d >> 7;
    int r = atomicAdd(&lcur[b], 1);
    binned[lofs[b] + r] = ((unsigned int)(d & 127) << 17) | (unsigned int)src[q];
  }
}

// ---- 4. per-bucket counting sort -> CSR + deg + isd + row_start ----
__global__ __launch_bounds__(256) void k_csr(const unsigned int* __restrict__ binned,
                                             const int* __restrict__ bbase,
                                             int* __restrict__ csr,
                                             int* __restrict__ deg,
                                             float* __restrict__ isd,
                                             int* __restrict__ row_start, int n) {
  int b = blockIdx.x;
  int lo = bbase[b], hi = bbase[b + 1];
  __shared__ int h[BN];
  __shared__ int sc[BN];
  __shared__ int cur[BN];
  int t = threadIdx.x;
  if (t < BN) h[t] = 0;
  __syncthreads();
  for (int q = lo + t; q < hi; q += 256) atomicAdd(&h[binned[q] >> 17], 1);
  __syncthreads();
  if (t < BN) sc[t] = h[t];
  __syncthreads();
  for (int off = 1; off < BN; off <<= 1) {
    int a = 0;
    if (t < BN && t >= off) a = sc[t - off];
    __syncthreads();
    if (t < BN) sc[t] += a;
    __syncthreads();
  }
  if (t < BN) {
    int excl = sc[t] - h[t];
    cur[t] = lo + excl;
    int i = b * BN + t;
    if (i < n) {
      deg[i] = h[t];
      isd[i] = rsqrtf((float)(h[t] + 1));
      row_start[i] = lo + excl;
    }
  }
  __syncthreads();
  for (int q = lo + t; q < hi; q += 256) {
    unsigned int u = binned[q];
    int p = atomicAdd(&cur[u >> 17], 1);
    csr[p] = (int)(u & 0x1FFFF);
  }
}

// ---- tiled GEMM: HS = isd[i] * (X @ W), fp32 accum, bf16 out ----
template <bool BF>
__global__ __launch_bounds__(256) void k_gemm_t(const void* __restrict__ Xv,
                                                const float* __restrict__ W,
                                                const float* __restrict__ isd,
                                                bf16* __restrict__ HS, int n) {
  __shared__ float Xt[64][D + 4];
  __shared__ float Wb[32][D + 4];
  int t = threadIdx.x;
  int r0 = blockIdx.x * 64;
  if (!BF) {
    const float* X = (const float*)Xv;
    for (int q = t; q < 64 * 32; q += 256) {
      int row = q >> 5, cb = (q & 31) << 2;
      float4 v = {0.f, 0.f, 0.f, 0.f};
      if (r0 + row < n) v = *(const float4*)(X + (size_t)(r0 + row) * D + cb);
      *(float4*)&Xt[row][cb] = v;
    }
  } else {
    const unsigned short* X = (const unsigned short*)Xv;
    for (int q = t; q < 64 * 16; q += 256) {
      int row = q >> 4, cb = (q & 15) << 3;
      uint4 v = {0u, 0u, 0u, 0u};
      if (r0 + row < n) v = *(const uint4*)(X + (size_t)(r0 + row) * D + cb);
      float* xp = &Xt[row][cb];
      xp[0] = b2f(v.x & 0xFFFF); xp[1] = b2f(v.x >> 16);
      xp[2] = b2f(v.y & 0xFFFF); xp[3] = b2f(v.y >> 16);
      xp[4] = b2f(v.z & 0xFFFF); xp[5] = b2f(v.z >> 16);
      xp[6] = b2f(v.w & 0xFFFF); xp[7] = b2f(v.w >> 16);
    }
  }
  int tr = ((t >> 4) & 15) << 2;
  int tc = (t & 15) << 3;
  float acc[4][8];
#pragma unroll
  for (int i = 0; i < 4; ++i)
#pragma unroll
    for (int j = 0; j < 8; ++j) acc[i][j] = 0.f;

  for (int hh = 0; hh < 4; ++hh) {
    __syncthreads();
    for (int q = t; q < 32 * 32; q += 256) {
      int row = q >> 5, cb = (q & 31) << 2;
      *(float4*)&Wb[row][cb] = *(const float4*)(W + (size_t)(hh * 32 + row) * D + cb);
    }
    __syncthreads();
#pragma unroll 4
    for (int k = 0; k < 32; ++k) {
      float4 u0 = *(const float4*)&Wb[k][tc];
      float4 u1 = *(const float4*)&Wb[k][tc + 4];
      float bv[8] = {u0.x, u0.y, u0.z, u0.w, u1.x, u1.y, u1.z, u1.w};
      int kk = hh * 32 + k;
#pragma unroll
      for (int i = 0; i < 4; ++i) {
        float a = Xt[tr + i][kk];
#pragma unroll
        for (int j = 0; j < 8; ++j) acc[i][j] += a * bv[j];
      }
    }
  }
#pragma unroll
  for (int i = 0; i < 4; ++i) {
    int row = r0 + tr + i;
    if (row < n) {
      float s = isd[row];
      unsigned short o[8];
#pragma unroll
      for (int j = 0; j < 8; ++j) o[j] = f2b(s * acc[i][j]);
      unsigned short* hp = (unsigned short*)HS + (size_t)row * D + tc;
      *(ushort4*)hp = *(ushort4*)&o[0];
      *(ushort4*)(hp + 4) = *(ushort4*)&o[4];
    }
  }
}

// ---- shared gather-accumulate core: unroll 8, 4 accumulator pairs ----
__device__ inline void gather_sum(const ushort2* __restrict__ hs2,
                                  const int* __restrict__ csr,
                                  int start, int c, int f,
                                  float& AX, float& AY) {
  float ax0 = AX, ay0 = AY, ax1 = 0.f, ay1 = 0.f;
  float ax2 = 0.f, ay2 = 0.f, ax3 = 0.f, ay3 = 0.f;
  for (int e0 = 0; e0 < c; e0 += 64) {
    int nb = min(64, c - e0);
    int idx = (f < nb) ? csr[start + e0 + f] : 0;
    int k = 0;
    for (; k + 8 <= nb; k += 8) {
      int s0 = __shfl(idx, k);
      int s1 = __shfl(idx, k + 1);
      int s2 = __shfl(idx, k + 2);
      int s3 = __shfl(idx, k + 3);
      int s4 = __shfl(idx, k + 4);
      int s5 = __shfl(idx, k + 5);
      int s6 = __shfl(idx, k + 6);
      int s7 = __shfl(idx, k + 7);
      ushort2 u0 = hs2[(size_t)s0 * 64 + f];
      ushort2 u1 = hs2[(size_t)s1 * 64 + f];
      ushort2 u2 = hs2[(size_t)s2 * 64 + f];
      ushort2 u3 = hs2[(size_t)s3 * 64 + f];
      ushort2 u4 = hs2[(size_t)s4 * 64 + f];
      ushort2 u5 = hs2[(size_t)s5 * 64 + f];
      ushort2 u6 = hs2[(size_t)s6 * 64 + f];
      ushort2 u7 = hs2[(size_t)s7 * 64 + f];
      ax0 += b2f(u0.x); ay0 += b2f(u0.y);
      ax1 += b2f(u1.x); ay1 += b2f(u1.y);
      ax2 += b2f(u2.x); ay2 += b2f(u2.y);
      ax3 += b2f(u3.x); ay3 += b2f(u3.y);
      ax0 += b2f(u4.x); ay0 += b2f(u4.y);
      ax1 += b2f(u5.x); ay1 += b2f(u5.y);
      ax2 += b2f(u6.x); ay2 += b2f(u6.y);
      ax3 += b2f(u7.x); ay3 += b2f(u7.y);
    }
    for (; k < nb; ++k) {
      int s = __shfl(idx, k);
      ushort2 u = hs2[(size_t)s * 64 + f];
      ax0 += b2f(u.x);
      ay0 += b2f(u.y);
    }
  }
  AX = (ax0 + ax1) + (ax2 + ax3);
  AY = (ay0 + ay1) + (ay2 + ay3);
}

// ---- agg + bias + relu -> bf16 ----
__global__ __launch_bounds__(64) void k_agg1(const bf16* __restrict__ HS,
                                             const int* __restrict__ csr,
                                             const int* __restrict__ row_start,
                                             const int* __restrict__ deg,
                                             const float* __restrict__ isd,
                                             const float* __restrict__ bias,
                                             bf16* __restrict__ G) {
  int i = blockIdx.x;
  int f = threadIdx.x;
  const ushort2* hs2 = (const ushort2*)HS;
  ushort2 v = hs2[(size_t)i * 64 + f];  // self-loop term (already isd[i]-scaled)
  float ax = b2f(v.x), ay = b2f(v.y);
  gather_sum(hs2, csr, row_start[i], deg[i], f, ax, ay);
  float di = isd[i];
  float gx = di * ax + bias[2 * f];
  float gy = di * ay + bias[2 * f + 1];
  gx = gx > 0.f ? gx : 0.f;
  gy = gy > 0.f ? gy : 0.f;
  ushort2 o;
  o.x = f2b(gx);
  o.y = f2b(gy);
  ((ushort2*)G)[(size_t)i * 64 + f] = o;
}

// ---- agg + bias + relu + classifier -> fp32 out ----
__global__ __launch_bounds__(64) void k_agg_cls(const bf16* __restrict__ HS,
                                                const int* __restrict__ csr,
                                                const int* __restrict__ row_start,
                                                const int* __restrict__ deg,
                                                const float* __restrict__ isd,
                                                const float* __restrict__ b2,
                                                const float* __restrict__ Wl,
                                                const float* __restrict__ bl,
                                                float* __restrict__ out) {
  int i = blockIdx.x;
  int f = threadIdx.x;
  const ushort2* hs2 = (const ushort2*)HS;
  ushort2 v = hs2[(size_t)i * 64 + f];
  float ax = b2f(v.x), ay = b2f(v.y);
  gather_sum(hs2, csr, row_start[i], deg[i], f, ax, ay);
  float di = isd[i];
  float gx = di * ax + b2[2 * f];
  float gy = di * ay + b2[2 * f + 1];
  gx = gx > 0.f ? gx : 0.f;
  gy = gy > 0.f ? gy : 0.f;
  __shared__ float tt[D];
  tt[2 * f] = gx;
  tt[2 * f + 1] = gy;
  __syncthreads();
  if (f < N_CLS) {
    float o = bl[f];
#pragma unroll 8
    for (int k = 0; k < D; ++k) o += tt[k] * Wl[k * N_CLS + f];
    out[(size_t)i * N_CLS + f] = o;
  }
}

extern "C" void kernel_launch(void* const* d_in, const int* in_sizes, int n_in,
                              void* d_out, int out_size, void* d_ws, size_t ws_size,
                              hipStream_t stream) {
  const float* x  = (const float*)d_in[0];
  const int*   ei = (const int*)d_in[1];
  const float* W1 = (const float*)d_in[2];
  const float* b1 = (const float*)d_in[3];
  const float* W2 = (const float*)d_in[4];
  const float* b2 = (const float*)d_in[5];
  const float* Wl = (const float*)d_in[6];
  const float* bl = (const float*)d_in[7];
  float* out = (float*)d_out;

  const int n = in_sizes[0] / D;  // 100000
  const int e = in_sizes[1] / 2;  // 3200000
  const int* src = ei;
  const int* dst = ei + e;
  const int nb = (n + BN - 1) / BN;  // 782

  char* ws = (char*)d_ws;
  size_t off = 0;
  auto alloc = [&](size_t bytes) -> void* {
    void* p = ws + off;
    off += (bytes + 255) & ~(size_t)255;
    return p;
  };
  int*   bcnt      = (int*)alloc(NBMAX * 4);
  int*   bbase     = (int*)alloc(NBMAX * 4);
  int*   bcur      = (int*)alloc(NBMAX * 4);
  int*   deg       = (int*)alloc((size_t)n * 4);
  int*   row_start = (int*)alloc((size_t)n * 4);
  float* isd       = (float*)alloc((size_t)n * 4);
  int*   csr       = (int*)alloc((size_t)e * 4);
  bf16*  hA        = (bf16*)alloc((size_t)n * D * 2);
  bf16*  hB        = (bf16*)alloc((size_t)n * D * 2);
  unsigned int* binned = (unsigned int*)hA;  // dead before gemm1 writes hA

  hipMemsetAsync(bcnt, 0, NBMAX * 4, stream);

  const int nwg_place = 512;
  k_hist<<<1024, 256, 0, stream>>>(dst, bcnt, e);
  k_bscan<<<1, 1024, 0, stream>>>(bcnt, bbase, bcur);
  k_place<<<nwg_place, 256, 0, stream>>>(src, dst, bcur, binned, e, nwg_place);
  k_csr<<<nb, 256, 0, stream>>>(binned, bbase, csr, deg, isd, row_start, n);

  int gblocks = (n + 63) / 64;
  // layer 1
  k_gemm_t<false><<<gblocks, 256, 0, stream>>>(x, W1, isd, hA, n);
  k_agg1<<<n, 64, 0, stream>>>(hA, csr, row_start, deg, isd, b1, hB);
  // layer 2 + classifier
  k_gemm_t<true><<<gblocks, 256, 0, stream>>>(hB, W2, isd, hA, n);
  k_agg_cls<<<n, 64, 0, stream>>>(hA, csr, row_start, deg, isd, b2, Wl, bl, out);
}

// Round 6
// 576.345 us; speedup vs baseline: 2.6844x; 1.0189x over previous
//
#include <hip/hip_runtime.h>
#include <hip/hip_bf16.h>

typedef _Float16 f16;
typedef _Float16 f16x8 __attribute__((ext_vector_type(8)));

#define D 128
#define N_CLS 40
#define BN 128       // nodes per bucket
#define NBMAX 1024   // padded bucket count

// ---- 1. bucket histogram of dst (LDS-staged) ----
__global__ __launch_bounds__(256) void k_hist(const int* __restrict__ dst,
                                              int* __restrict__ bcnt, int e) {
  __shared__ int lh[NBMAX];
  for (int j = threadIdx.x; j < NBMAX; j += 256) lh[j] = 0;
  __syncthreads();
  int stride = gridDim.x * blockDim.x;
  for (int q = blockIdx.x * blockDim.x + threadIdx.x; q < e; q += stride)
    atomicAdd(&lh[dst[q] >> 7], 1);
  __syncthreads();
  for (int j = threadIdx.x; j < NBMAX; j += 256)
    if (lh[j]) atomicAdd(&bcnt[j], lh[j]);
}

// ---- 2. exclusive scan of bucket counts ----
__global__ __launch_bounds__(1024) void k_bscan(const int* __restrict__ bcnt,
                                                int* __restrict__ bbase,
                                                int* __restrict__ bcur) {
  __shared__ int sums[NBMAX];
  int t = threadIdx.x;
  int c = bcnt[t];
  sums[t] = c;
  __syncthreads();
  for (int off = 1; off < NBMAX; off <<= 1) {
    int a = (t >= off) ? sums[t - off] : 0;
    __syncthreads();
    sums[t] += a;
    __syncthreads();
  }
  bbase[t] = sums[t] - c;
  bcur[t] = sums[t] - c;
}

// ---- 3. bin edges into bucket-major order ----
__global__ __launch_bounds__(256) void k_place(const int* __restrict__ src,
                                               const int* __restrict__ dst,
                                               int* __restrict__ bcur,
                                               unsigned int* __restrict__ binned,
                                               int e, int nwg) {
  __shared__ int lh[NBMAX];
  __shared__ int lofs[NBMAX];
  __shared__ int lcur[NBMAX];
  int chunk = (e + nwg - 1) / nwg;
  int lo = blockIdx.x * chunk;
  int hi = min(e, lo + chunk);
  int t = threadIdx.x;
  for (int j = t; j < NBMAX; j += 256) { lh[j] = 0; lcur[j] = 0; }
  __syncthreads();
  for (int q = lo + t; q < hi; q += 256) atomicAdd(&lh[dst[q] >> 7], 1);
  __syncthreads();
  for (int j = t; j < NBMAX; j += 256) {
    int c = lh[j];
    lofs[j] = c ? atomicAdd(&bcur[j], c) : 0;
  }
  __syncthreads();
  for (int q = lo + t; q < hi; q += 256) {
    int d = dst[q];
    int b = d >> 7;
    int r = atomicAdd(&lcur[b], 1);
    binned[lofs[b] + r] = ((unsigned int)(d & 127) << 17) | (unsigned int)src[q];
  }
}

// ---- 4. per-bucket counting sort -> CSR + deg + isd + row_start ----
__global__ __launch_bounds__(256) void k_csr(const unsigned int* __restrict__ binned,
                                             const int* __restrict__ bbase,
                                             int* __restrict__ csr,
                                             int* __restrict__ deg,
                                             float* __restrict__ isd,
                                             int* __restrict__ row_start, int n) {
  int b = blockIdx.x;
  int lo = bbase[b], hi = bbase[b + 1];
  __shared__ int h[BN];
  __shared__ int sc[BN];
  __shared__ int cur[BN];
  int t = threadIdx.x;
  if (t < BN) h[t] = 0;
  __syncthreads();
  for (int q = lo + t; q < hi; q += 256) atomicAdd(&h[binned[q] >> 17], 1);
  __syncthreads();
  if (t < BN) sc[t] = h[t];
  __syncthreads();
  for (int off = 1; off < BN; off <<= 1) {
    int a = 0;
    if (t < BN && t >= off) a = sc[t - off];
    __syncthreads();
    if (t < BN) sc[t] += a;
    __syncthreads();
  }
  if (t < BN) {
    int excl = sc[t] - h[t];
    cur[t] = lo + excl;
    int i = b * BN + t;
    if (i < n) {
      deg[i] = h[t];
      isd[i] = rsqrtf((float)(h[t] + 1));
      row_start[i] = lo + excl;
    }
  }
  __syncthreads();
  for (int q = lo + t; q < hi; q += 256) {
    unsigned int u = binned[q];
    int p = atomicAdd(&cur[u >> 17], 1);
    csr[p] = (int)(u & 0x1FFFF);
  }
}

// ---- tiled GEMM: HS = isd[i] * (X @ W), fp32 accum, f16 out ----
template <bool HALF_IN>
__global__ __launch_bounds__(256) void k_gemm_t(const void* __restrict__ Xv,
                                                const float* __restrict__ W,
                                                const float* __restrict__ isd,
                                                f16* __restrict__ HS, int n) {
  __shared__ float Xt[64][D + 4];
  __shared__ float Wb[32][D + 4];
  int t = threadIdx.x;
  int r0 = blockIdx.x * 64;
  if (!HALF_IN) {
    const float* X = (const float*)Xv;
    for (int q = t; q < 64 * 32; q += 256) {
      int row = q >> 5, cb = (q & 31) << 2;
      float4 v = {0.f, 0.f, 0.f, 0.f};
      if (r0 + row < n) v = *(const float4*)(X + (size_t)(r0 + row) * D + cb);
      *(float4*)&Xt[row][cb] = v;
    }
  } else {
    const f16* X = (const f16*)Xv;
    for (int q = t; q < 64 * 16; q += 256) {
      int row = q >> 4, cb = (q & 15) << 3;
      f16x8 v = 0;
      if (r0 + row < n) v = *(const f16x8*)(X + (size_t)(r0 + row) * D + cb);
      float* xp = &Xt[row][cb];
#pragma unroll
      for (int j = 0; j < 8; ++j) xp[j] = (float)v[j];
    }
  }
  int tr = ((t >> 4) & 15) << 2;
  int tc = (t & 15) << 3;
  float acc[4][8];
#pragma unroll
  for (int i = 0; i < 4; ++i)
#pragma unroll
    for (int j = 0; j < 8; ++j) acc[i][j] = 0.f;

  for (int hh = 0; hh < 4; ++hh) {
    __syncthreads();
    for (int q = t; q < 32 * 32; q += 256) {
      int row = q >> 5, cb = (q & 31) << 2;
      *(float4*)&Wb[row][cb] = *(const float4*)(W + (size_t)(hh * 32 + row) * D + cb);
    }
    __syncthreads();
#pragma unroll 4
    for (int k = 0; k < 32; ++k) {
      float4 u0 = *(const float4*)&Wb[k][tc];
      float4 u1 = *(const float4*)&Wb[k][tc + 4];
      float bv[8] = {u0.x, u0.y, u0.z, u0.w, u1.x, u1.y, u1.z, u1.w};
      int kk = hh * 32 + k;
#pragma unroll
      for (int i = 0; i < 4; ++i) {
        float a = Xt[tr + i][kk];
#pragma unroll
        for (int j = 0; j < 8; ++j) acc[i][j] += a * bv[j];
      }
    }
  }
#pragma unroll
  for (int i = 0; i < 4; ++i) {
    int row = r0 + tr + i;
    if (row < n) {
      float s = isd[row];
      f16x8 ov;
#pragma unroll
      for (int j = 0; j < 8; ++j) ov[j] = (f16)(s * acc[i][j]);
      *(f16x8*)(HS + (size_t)row * D + tc) = ov;
    }
  }
}

// ---- gather core: 4 edges/wave via 16-lane x 16B loads, pk_f16 accumulate ----
// lane layout: g = lane>>4 (edge subgroup 0..3), l = lane&15 (features l*8..l*8+7)
// On return acc[0..7] holds, in EVERY lane, the summed features (lane&15)*8+j.
__device__ inline void gather8(const f16* __restrict__ HS,
                               const int* __restrict__ csr,
                               int start, int c, int lane, float acc[8]) {
  int g = lane >> 4;
  int l = lane & 15;
  const char* base = (const char*)HS;
  size_t lofs = (size_t)(l << 4);
#pragma unroll
  for (int j = 0; j < 8; ++j) acc[j] = 0.f;

  for (int e0 = 0; e0 < c; e0 += 64) {
    int nb = min(64, c - e0);
    int idx = (lane < nb) ? csr[start + e0 + lane] : 0;
    int kb = 0;
    // full 16-edge runs: f16 packed accumulate, fp32 flush per run
    for (; kb + 16 <= nb; kb += 16) {
      f16x8 a16 = 0;
#pragma unroll
      for (int k = 0; k < 16; k += 4) {
        int s = __shfl(idx, kb + k + g);
        a16 += *(const f16x8*)(base + (((size_t)s) << 8) + lofs);
      }
#pragma unroll
      for (int j = 0; j < 8; ++j) acc[j] += (float)a16[j];
    }
    // tail (<16 edges): masked packed accumulate
    if (kb < nb) {
      f16x8 a16 = 0;
      for (int k = kb; k < nb; k += 4) {
        int kk = k + g;  // <= 63 always
        int s = __shfl(idx, kk);
        f16x8 u = *(const f16x8*)(base + (((size_t)s) << 8) + lofs);
        if (kk < nb) a16 += u;
      }
#pragma unroll
      for (int j = 0; j < 8; ++j) acc[j] += (float)a16[j];
    }
  }
  // merge the 4 edge subgroups (lanes differ in bits 4,5)
#pragma unroll
  for (int j = 0; j < 8; ++j) {
    float v = acc[j];
    v += __shfl_xor(v, 16);
    v += __shfl_xor(v, 32);
    acc[j] = v;
  }
}

// ---- agg + bias + relu -> f16 ----
__global__ __launch_bounds__(64) void k_agg1(const f16* __restrict__ HS,
                                             const int* __restrict__ csr,
                                             const int* __restrict__ row_start,
                                             const int* __restrict__ deg,
                                             const float* __restrict__ isd,
                                             const float* __restrict__ bias,
                                             f16* __restrict__ G) {
  int i = blockIdx.x;
  int lane = threadIdx.x;
  int l = lane & 15;
  float acc[8];
  gather8(HS, csr, row_start[i], deg[i], lane, acc);
  // self-loop row
  f16x8 sv = *(const f16x8*)(HS + (size_t)i * D + l * 8);
  float di = isd[i];
  float4 bb0 = *(const float4*)(bias + l * 8);
  float4 bb1 = *(const float4*)(bias + l * 8 + 4);
  float bv[8] = {bb0.x, bb0.y, bb0.z, bb0.w, bb1.x, bb1.y, bb1.z, bb1.w};
  f16x8 ov;
#pragma unroll
  for (int j = 0; j < 8; ++j) {
    float v = di * (acc[j] + (float)sv[j]) + bv[j];
    v = v > 0.f ? v : 0.f;
    ov[j] = (f16)v;
  }
  if ((lane >> 4) == 0) *(f16x8*)(G + (size_t)i * D + l * 8) = ov;
}

// ---- agg + bias + relu + classifier -> fp32 out ----
__global__ __launch_bounds__(64) void k_agg_cls(const f16* __restrict__ HS,
                                                const int* __restrict__ csr,
                                                const int* __restrict__ row_start,
                                                const int* __restrict__ deg,
                                                const float* __restrict__ isd,
                                                const float* __restrict__ b2,
                                                const float* __restrict__ Wl,
                                                const float* __restrict__ bl,
                                                float* __restrict__ out) {
  int i = blockIdx.x;
  int lane = threadIdx.x;
  int l = lane & 15;
  float acc[8];
  gather8(HS, csr, row_start[i], deg[i], lane, acc);
  f16x8 sv = *(const f16x8*)(HS + (size_t)i * D + l * 8);
  float di = isd[i];
  float4 bb0 = *(const float4*)(b2 + l * 8);
  float4 bb1 = *(const float4*)(b2 + l * 8 + 4);
  float bv[8] = {bb0.x, bb0.y, bb0.z, bb0.w, bb1.x, bb1.y, bb1.z, bb1.w};
  __shared__ float tt[D];
#pragma unroll
  for (int j = 0; j < 8; ++j) {
    float v = di * (acc[j] + (float)sv[j]) + bv[j];
    bv[j] = v > 0.f ? v : 0.f;
  }
  if ((lane >> 4) == 0) {
    *(float4*)&tt[l * 8] = make_float4(bv[0], bv[1], bv[2], bv[3]);
    *(float4*)&tt[l * 8 + 4] = make_float4(bv[4], bv[5], bv[6], bv[7]);
  }
  __syncthreads();
  if (lane < N_CLS) {
    float o = bl[lane];
#pragma unroll 8
    for (int k = 0; k < D; ++k) o += tt[k] * Wl[k * N_CLS + lane];
    out[(size_t)i * N_CLS + lane] = o;
  }
}

extern "C" void kernel_launch(void* const* d_in, const int* in_sizes, int n_in,
                              void* d_out, int out_size, void* d_ws, size_t ws_size,
                              hipStream_t stream) {
  const float* x  = (const float*)d_in[0];
  const int*   ei = (const int*)d_in[1];
  const float* W1 = (const float*)d_in[2];
  const float* b1 = (const float*)d_in[3];
  const float* W2 = (const float*)d_in[4];
  const float* b2 = (const float*)d_in[5];
  const float* Wl = (const float*)d_in[6];
  const float* bl = (const float*)d_in[7];
  float* out = (float*)d_out;

  const int n = in_sizes[0] / D;  // 100000
  const int e = in_sizes[1] / 2;  // 3200000
  const int* src = ei;
  const int* dst = ei + e;
  const int nb = (n + BN - 1) / BN;  // 782

  char* ws = (char*)d_ws;
  size_t off = 0;
  auto alloc = [&](size_t bytes) -> void* {
    void* p = ws + off;
    off += (bytes + 255) & ~(size_t)255;
    return p;
  };
  int*   bcnt      = (int*)alloc(NBMAX * 4);
  int*   bbase     = (int*)alloc(NBMAX * 4);
  int*   bcur      = (int*)alloc(NBMAX * 4);
  int*   deg       = (int*)alloc((size_t)n * 4);
  int*   row_start = (int*)alloc((size_t)n * 4);
  float* isd       = (float*)alloc((size_t)n * 4);
  int*   csr       = (int*)alloc((size_t)e * 4);
  f16*   hA        = (f16*)alloc((size_t)n * D * 2);
  f16*   hB        = (f16*)alloc((size_t)n * D * 2);
  unsigned int* binned = (unsigned int*)hA;  // dead before gemm1 writes hA

  hipMemsetAsync(bcnt, 0, NBMAX * 4, stream);

  const int nwg_place = 512;
  k_hist<<<1024, 256, 0, stream>>>(dst, bcnt, e);
  k_bscan<<<1, 1024, 0, stream>>>(bcnt, bbase, bcur);
  k_place<<<nwg_place, 256, 0, stream>>>(src, dst, bcur, binned, e, nwg_place);
  k_csr<<<nb, 256, 0, stream>>>(binned, bbase, csr, deg, isd, row_start, n);

  int gblocks = (n + 63) / 64;
  // layer 1
  k_gemm_t<false><<<gblocks, 256, 0, stream>>>(x, W1, isd, hA, n);
  k_agg1<<<n, 64, 0, stream>>>(hA, csr, row_start, deg, isd, b1, hB);
  // layer 2 + classifier
  k_gemm_t<true><<<gblocks, 256, 0, stream>>>(hB, W2, isd, hA, n);
  k_agg_cls<<<n, 64, 0, stream>>>(hA, csr, row_start, deg, isd, b2, Wl, bl, out);
}